// Round 3
// baseline (1100.556 us; speedup 1.0000x reference)
//
#include <hip/hip_runtime.h>
#include <hip/hip_bf16.h>
#include <math.h>

#define BB 64
#define OO 32
#define II 2048
#define DD 16
#define CAPS_EPS 1e-12f

// t_const = ln(0.9*31) - ln(0.1) = ln(279)
#define T_CONST 5.6312118f

// workspace float offsets (part LAST so its size can flex with ws_size)
#define OFF_DSUM 0ULL                        // 2 floats
#define OFF_T    2ULL                        // 2 floats
#define OFF_V    16ULL                       // 32768 floats: v [B][O][D]
#define OFF_D    (16ULL + 32768ULL)          // 4194304 floats: d [I][2][B][16]
#define OFF_CT   (OFF_D + 4194304ULL)        // 4194304 floats: ct [I][B][O]
#define OFF_UHAT (OFF_CT + 4194304ULL)       // 33554432 float-slots: uhat bf16 [I][B][O][D]
#define OFF_PART (OFF_UHAT + 33554432ULL)    // GX*32768 floats

__device__ __forceinline__ float bf16_lo(unsigned v) {
    union { unsigned u; float f; } c; c.u = v << 16; return c.f;
}
__device__ __forceinline__ float bf16_hi(unsigned v) {
    union { unsigned u; float f; } c; c.u = v & 0xffff0000u; return c.f;
}
__device__ __forceinline__ unsigned pack_bf16(float a, float b) {
    __hip_bfloat16 ha = __float2bfloat16(a), hb = __float2bfloat16(b);
    unsigned short sa, sb;
    __builtin_memcpy(&sa, &ha, 2); __builtin_memcpy(&sb, &hb, 2);
    return (unsigned)sa | ((unsigned)sb << 16);
}

__global__ void init_kernel(float* ws) {
    if (threadIdx.x == 0 && blockIdx.x == 0) {
        ws[OFF_DSUM + 0] = 0.f;
        ws[OFF_DSUM + 1] = 0.f;
    }
}

// Pure transform: u_hat (scaled, bf16) <- W, u.  grid (II/TI, 2), 256 thr.
template<int TI>
__global__ __launch_bounds__(256) void uhat_kernel(
    const float* __restrict__ u,   // [B][I][16]
    const float* __restrict__ W,   // [O][I][16][16]
    unsigned* __restrict__ uhat)   // [I][B][O][8] packed bf16 pairs
{
    const int ic   = blockIdx.x;
    const int og2  = blockIdx.y;
    const int wave = threadIdx.x >> 6;
    const int b    = threadIdx.x & 63;
    const int o_base = og2 * 16 + wave * 4;

    #pragma unroll
    for (int ii = 0; ii < TI; ++ii) {
        const int i = ic * TI + ii;

        float ureg[DD];
        {
            const float4* up = reinterpret_cast<const float4*>(
                u + ((size_t)b * II + i) * DD);
            #pragma unroll
            for (int q = 0; q < 4; ++q) {
                float4 t4 = up[q];
                ureg[4*q+0] = t4.x; ureg[4*q+1] = t4.y;
                ureg[4*q+2] = t4.z; ureg[4*q+3] = t4.w;
            }
        }
        float un2 = 0.f;
        #pragma unroll
        for (int k = 0; k < DD; ++k) un2 += ureg[k] * ureg[k];
        const float unorm = sqrtf(un2);

        #pragma unroll
        for (int ol = 0; ol < 4; ++ol) {
            const int o = o_base + ol;
            const float4* wp = reinterpret_cast<const float4*>(
                W + ((size_t)o * II + i) * (DD * DD));
            float uh[DD];
            float n2 = 0.f;
            #pragma unroll
            for (int d2 = 0; d2 < DD; ++d2) {
                float acc = 0.f;
                #pragma unroll
                for (int q = 0; q < 4; ++q) {
                    float4 w4 = wp[d2 * 4 + q];
                    acc += w4.x * ureg[4*q+0] + w4.y * ureg[4*q+1]
                         + w4.z * ureg[4*q+2] + w4.w * ureg[4*q+3];
                }
                uh[d2] = acc;
                n2 += acc * acc;
            }
            const float rawn  = sqrtf(n2);
            const float scale = fminf(rawn, unorm) / (rawn + CAPS_EPS);
            #pragma unroll
            for (int d = 0; d < DD; ++d) uh[d] *= scale;

            unsigned* outp = uhat + ((((size_t)i * BB + b) * OO) + o) * 8;
            uint4 p0, p1;
            p0.x = pack_bf16(uh[0],  uh[1]);  p0.y = pack_bf16(uh[2],  uh[3]);
            p0.z = pack_bf16(uh[4],  uh[5]);  p0.w = pack_bf16(uh[6],  uh[7]);
            p1.x = pack_bf16(uh[8],  uh[9]);  p1.y = pack_bf16(uh[10], uh[11]);
            p1.z = pack_bf16(uh[12], uh[13]); p1.w = pack_bf16(uh[14], uh[15]);
            reinterpret_cast<uint4*>(outp)[0] = p0;
            reinterpret_cast<uint4*>(outp)[1] = p1;
        }
    }
}

// s-stages: STAGE 0 (c=1/32), 2 (softmax t0), 4 (softmax t1 + write c).
// grid (GX, 2), 256 thr, TI = II/GX.
template<int STAGE, int TI>
__global__ __launch_bounds__(256) void sstage_kernel(
    const unsigned* __restrict__ uhat,
    float* __restrict__ ws,
    float* __restrict__ part,
    float* __restrict__ ct)
{
    const int ic   = blockIdx.x;
    const int og2  = blockIdx.y;
    const int wave = threadIdx.x >> 6;
    const int b    = threadIdx.x & 63;
    const int o_base = og2 * 16 + wave * 4;

    const float* d_ws = ws + OFF_D;

    float s_acc[4][DD];
    #pragma unroll
    for (int ol = 0; ol < 4; ++ol)
        #pragma unroll
        for (int d = 0; d < DD; ++d) s_acc[ol][d] = 0.f;

    float tval = 0.f;
    if (STAGE == 2) tval = ws[OFF_T + 0];
    if (STAGE == 4) tval = ws[OFF_T + 1];

    #pragma unroll
    for (int ii = 0; ii < TI; ++ii) {
        const int i = ic * TI + ii;

        uint4 q[8];
        {
            const uint4* up = reinterpret_cast<const uint4*>(
                uhat + (((size_t)i * BB + b) * OO + o_base) * 8);
            #pragma unroll
            for (int j = 0; j < 8; ++j) q[j] = up[j];
        }

        float c_here[4];
        if (STAGE == 0) {
            #pragma unroll
            for (int ol = 0; ol < 4; ++ol) c_here[ol] = 1.0f / OO;
        } else {
            float bv[OO];
            #pragma unroll
            for (int h = 0; h < 2; ++h) {
                const float4* dp = reinterpret_cast<const float4*>(
                    d_ws + (((size_t)i * 2 + h) * BB + b) * 16);
                #pragma unroll
                for (int qq = 0; qq < 4; ++qq) {
                    float4 t4 = dp[qq];
                    bv[h*16+4*qq+0] = tval * t4.x; bv[h*16+4*qq+1] = tval * t4.y;
                    bv[h*16+4*qq+2] = tval * t4.z; bv[h*16+4*qq+3] = tval * t4.w;
                }
            }
            float m = -1e30f;
            #pragma unroll
            for (int o = 0; o < OO; ++o) m = fmaxf(m, bv[o]);
            float ssum = 0.f;
            #pragma unroll
            for (int o = 0; o < OO; ++o) { bv[o] = __expf(bv[o] - m); ssum += bv[o]; }
            const float inv = 1.f / ssum;
            #pragma unroll
            for (int ol = 0; ol < 4; ++ol) c_here[ol] = bv[o_base + ol] * inv;
            if (STAGE == 4) {
                float4 cw = make_float4(c_here[0], c_here[1], c_here[2], c_here[3]);
                *reinterpret_cast<float4*>(
                    ct + ((size_t)i * BB + b) * OO + o_base) = cw;
            }
        }

        #pragma unroll
        for (int ol = 0; ol < 4; ++ol) {
            const float cc = c_here[ol];
            #pragma unroll
            for (int j = 0; j < 4; ++j) {
                unsigned w0 = (&q[2*ol].x)[j];
                s_acc[ol][2*j+0] += cc * bf16_lo(w0);
                s_acc[ol][2*j+1] += cc * bf16_hi(w0);
                unsigned w1 = (&q[2*ol+1].x)[j];
                s_acc[ol][8+2*j+0] += cc * bf16_lo(w1);
                s_acc[ol][8+2*j+1] += cc * bf16_hi(w1);
            }
        }
    }

    #pragma unroll
    for (int ol = 0; ol < 4; ++ol)
        #pragma unroll
        for (int d = 0; d < DD; ++d)
            part[(((size_t)ic * BB + b) * OO + o_base + ol) * DD + d] = s_acc[ol][d];
}

// d-stages: SLOT 0 (after v0), 1 (after v1). grid (II/TI, 2), 256 thr.
template<int SLOT, int TI>
__global__ __launch_bounds__(256) void dstage_kernel(
    const unsigned* __restrict__ uhat,
    float* __restrict__ ws)
{
    const int ic   = blockIdx.x;
    const int og2  = blockIdx.y;
    const int wave = threadIdx.x >> 6;
    const int b    = threadIdx.x & 63;
    const int o_base = og2 * 16 + wave * 4;

    float* d_ws       = ws + OFF_D;
    const float* v_ws = ws + OFF_V;

    float vreg[4][DD];
    #pragma unroll
    for (int ol = 0; ol < 4; ++ol) {
        const float4* vp = reinterpret_cast<const float4*>(
            v_ws + ((size_t)b * OO + o_base + ol) * DD);
        #pragma unroll
        for (int q = 0; q < 4; ++q) {
            float4 t4 = vp[q];
            vreg[ol][4*q+0] = t4.x; vreg[ol][4*q+1] = t4.y;
            vreg[ol][4*q+2] = t4.z; vreg[ol][4*q+3] = t4.w;
        }
    }

    float dsum_local = 0.f;

    #pragma unroll
    for (int ii = 0; ii < TI; ++ii) {
        const int i = ic * TI + ii;

        uint4 q[8];
        {
            const uint4* up = reinterpret_cast<const uint4*>(
                uhat + (((size_t)i * BB + b) * OO + o_base) * 8);
            #pragma unroll
            for (int j = 0; j < 8; ++j) q[j] = up[j];
        }

        float dist[4];
        #pragma unroll
        for (int ol = 0; ol < 4; ++ol) {
            float dist2 = 0.f;
            #pragma unroll
            for (int j = 0; j < 4; ++j) {
                unsigned w0 = (&q[2*ol].x)[j];
                float df0 = vreg[ol][2*j+0] - bf16_lo(w0);
                float df1 = vreg[ol][2*j+1] - bf16_hi(w0);
                dist2 += df0*df0 + df1*df1;
                unsigned w1 = (&q[2*ol+1].x)[j];
                float df2 = vreg[ol][8+2*j+0] - bf16_lo(w1);
                float df3 = vreg[ol][8+2*j+1] - bf16_hi(w1);
                dist2 += df2*df2 + df3*df3;
            }
            dist[ol] = sqrtf(dist2);
            dsum_local += dist[ol];
        }
        // d layout [i][og2][b][16o]: one float4 per lane, block covers 64 B/b-row
        *reinterpret_cast<float4*>(
            d_ws + (((size_t)i * 2 + og2) * BB + b) * 16 + wave * 4) =
            make_float4(dist[0], dist[1], dist[2], dist[3]);
    }

    #pragma unroll
    for (int off = 32; off > 0; off >>= 1)
        dsum_local += __shfl_down(dsum_local, off);
    __shared__ float red[4];
    if (b == 0) red[wave] = dsum_local;
    __syncthreads();
    if (threadIdx.x == 0) {
        float t = red[0] + red[1] + red[2] + red[3];
        atomicAdd(&ws[OFF_DSUM + SLOT], t);
    }
}

// ct [I][J] (J = b*32+o) -> out [J][I], LDS-tiled transpose
__global__ __launch_bounds__(256) void transpose_kernel(
    const float* __restrict__ src, float* __restrict__ dst)
{
    __shared__ float tile[32][33];
    const int tx = threadIdx.x & 31;
    const int ty = threadIdx.x >> 5;
    const int i0 = blockIdx.y * 32;
    const int j0 = blockIdx.x * 32;
    #pragma unroll
    for (int k = 0; k < 4; ++k)
        tile[ty + k*8][tx] = src[(size_t)(i0 + ty + k*8) * 2048 + j0 + tx];
    __syncthreads();
    #pragma unroll
    for (int k = 0; k < 4; ++k)
        dst[(size_t)(j0 + ty + k*8) * 2048 + i0 + tx] = tile[tx][ty + k*8];
}

__global__ __launch_bounds__(256) void finv_kernel(
    const float* __restrict__ part, const float* __restrict__ bias,
    float* __restrict__ vout, int ICHUNKS)
{
    const int tid = blockIdx.x * 256 + threadIdx.x;  // b*512 + o*16 + d
    float s = 0.f;
    for (int ic = 0; ic < ICHUNKS; ++ic) s += part[(size_t)ic * 32768 + tid];
    s += bias[tid & 511];
    float n2 = s * s;
    #pragma unroll
    for (int off = 1; off < 16; off <<= 1) n2 += __shfl_xor(n2, off);
    const float val = s * (n2 / (1.f + n2)) * rsqrtf(n2 + CAPS_EPS);
    vout[tid] = val;
}

__global__ void fint_kernel(float* ws, int slot) {
    if (threadIdx.x == 0 && blockIdx.x == 0) {
        const float d_o = ws[OFF_DSUM + slot] * (1.0f / (float)((size_t)BB * OO * II));
        ws[OFF_T + slot] = T_CONST / (-0.5f * d_o + 1e-12f);
    }
}

extern "C" void kernel_launch(void* const* d_in, const int* in_sizes, int n_in,
                              void* d_out, int out_size, void* d_ws, size_t ws_size,
                              hipStream_t stream) {
    const float* u    = (const float*)d_in[0];
    const float* W    = (const float*)d_in[1];
    const float* bias = (const float*)d_in[2];
    float* out = (float*)d_out;
    float* ws  = (float*)d_ws;

    float* part      = ws + OFF_PART;
    float* v_ws      = ws + OFF_V;
    float* ct        = ws + OFF_CT;
    unsigned* uhat   = (unsigned*)(ws + OFF_UHAT);
    float* cout      = out + (size_t)BB * OO * DD;

    // s-stage grid: 512 i-chunks if ws affords the bigger part buffer
    const size_t availF = ws_size / 4;
    const size_t budget = (availF > OFF_PART) ? (availF - OFF_PART) : 0;
    const int GX = (budget >= 512ULL * 32768ULL) ? 512 : 256;

    dim3 blk(256);
    dim3 grid_u(1024, 2);   // uhat: TI=2
    dim3 grid_d(1024, 2);   // d-stages: TI=2
    dim3 grid_s(GX, 2);     // s-stages

    init_kernel<<<1, 64, 0, stream>>>(ws);
    uhat_kernel<2><<<grid_u, blk, 0, stream>>>(u, W, uhat);

    if (GX == 512) {
        sstage_kernel<0, 4><<<grid_s, blk, 0, stream>>>(uhat, ws, part, ct);
        finv_kernel<<<128, 256, 0, stream>>>(part, bias, v_ws, GX);
        dstage_kernel<0, 2><<<grid_d, blk, 0, stream>>>(uhat, ws);
        fint_kernel<<<1, 64, 0, stream>>>(ws, 0);
        sstage_kernel<2, 4><<<grid_s, blk, 0, stream>>>(uhat, ws, part, ct);
        finv_kernel<<<128, 256, 0, stream>>>(part, bias, v_ws, GX);
        dstage_kernel<1, 2><<<grid_d, blk, 0, stream>>>(uhat, ws);
        fint_kernel<<<1, 64, 0, stream>>>(ws, 1);
        sstage_kernel<4, 4><<<grid_s, blk, 0, stream>>>(uhat, ws, part, ct);
        finv_kernel<<<128, 256, 0, stream>>>(part, bias, out, GX);
    } else {
        sstage_kernel<0, 8><<<grid_s, blk, 0, stream>>>(uhat, ws, part, ct);
        finv_kernel<<<128, 256, 0, stream>>>(part, bias, v_ws, GX);
        dstage_kernel<0, 2><<<grid_d, blk, 0, stream>>>(uhat, ws);
        fint_kernel<<<1, 64, 0, stream>>>(ws, 0);
        sstage_kernel<2, 8><<<grid_s, blk, 0, stream>>>(uhat, ws, part, ct);
        finv_kernel<<<128, 256, 0, stream>>>(part, bias, v_ws, GX);
        dstage_kernel<1, 2><<<grid_d, blk, 0, stream>>>(uhat, ws);
        fint_kernel<<<1, 64, 0, stream>>>(ws, 1);
        sstage_kernel<4, 8><<<grid_s, blk, 0, stream>>>(uhat, ws, part, ct);
        finv_kernel<<<128, 256, 0, stream>>>(part, bias, out, GX);
    }
    transpose_kernel<<<dim3(64, 64), 256, 0, stream>>>(ct, cout);
}

// Round 4
// 648.799 us; speedup vs baseline: 1.6963x; 1.6963x over previous
//
#include <hip/hip_runtime.h>
#include <hip/hip_bf16.h>
#include <math.h>

#define BB 64
#define OO 32
#define II 2048
#define DD 16
#define CAPS_EPS 1e-12f
#define T_CONST 5.6312118f   // ln(0.9*31) - ln(0.1)

// grids
#define GXU 256   // uhat_s0: grid (GXU,4), TI=8
#define TIU 8
#define GXD 512   // dstage:  grid (GXD,4), TI=4
#define TID 4
#define GXS 256   // sstage:  grid (GXS,4), TI=8
#define TIS 8

// workspace float offsets (total = 50,364,432 floats = 201,457,728 B; ws_size
// >= that, proven by R2 which gated the same figure and ran the gated path)
#define OFF_DSUM 0ULL
#define OFF_T    2ULL
#define OFF_V    16ULL                         // 32768: v [B][O][D]
#define OFF_D    (16ULL + 32768ULL)            // 4194304: d [I][og4][w][B][2]
#define OFF_CT   (OFF_D + 4194304ULL)          // 4194304: c [I][og4][w][B][2]
#define OFF_UHAT (OFF_CT + 4194304ULL)         // 33554432 slots: uhat bf16 [I][O][B][D]
#define OFF_PART (OFF_UHAT + 33554432ULL)      // 8388608: partials

__device__ __forceinline__ float bf16_lo(unsigned v) {
    union { unsigned u; float f; } c; c.u = v << 16; return c.f;
}
__device__ __forceinline__ float bf16_hi(unsigned v) {
    union { unsigned u; float f; } c; c.u = v & 0xffff0000u; return c.f;
}
__device__ __forceinline__ unsigned pack_bf16(float a, float b) {
    __hip_bfloat16 ha = __float2bfloat16(a), hb = __float2bfloat16(b);
    unsigned short sa, sb;
    __builtin_memcpy(&sa, &ha, 2); __builtin_memcpy(&sb, &hb, 2);
    return (unsigned)sa | ((unsigned)sb << 16);
}

__global__ void init_kernel(float* ws) {
    if (threadIdx.x == 0 && blockIdx.x == 0) {
        ws[OFF_DSUM + 0] = 0.f;
        ws[OFF_DSUM + 1] = 0.f;
    }
}

// -------- pass 1: u_hat (scaled, bf16, [i][o][b][d]) + s0 partials (c=1/32) --------
// grid (GXU, 4), block 256.  W for the block's 8 o's staged in LDS per i;
// compute reads W via broadcast ds_read_b128 (no per-lane VMEM storm).
__global__ __launch_bounds__(256) void uhat_s0_kernel(
    const float* __restrict__ u,   // [B][I][16]
    const float* __restrict__ W,   // [O][I][16][16]
    unsigned* __restrict__ uhat,   // [I][O][B][8] packed bf16 pairs
    float* __restrict__ part)      // [og4*GXU+ic][b][8o][16d]
{
    const int og4  = blockIdx.y;           // 0..3
    const int wave = threadIdx.x >> 6;     // 0..3
    const int b    = threadIdx.x & 63;
    const int o2   = wave * 2;             // local o base within block's 8

    __shared__ float Wl[8 * 256];          // [o_local][d][k]

    float s_acc[2][DD];
    #pragma unroll
    for (int ol = 0; ol < 2; ++ol)
        #pragma unroll
        for (int d = 0; d < DD; ++d) s_acc[ol][d] = 0.f;

    for (int ii = 0; ii < TIU; ++ii) {
        const int i = blockIdx.x * TIU + ii;

        __syncthreads();
        // stage 8 o x 1KB = 8 KB of W, coalesced: 256 thr x 2 float4
        #pragma unroll
        for (int q = 0; q < 2; ++q) {
            const int j   = q * 256 + threadIdx.x;
            const int o_l = j >> 6, r = j & 63;
            const float4 w4 = reinterpret_cast<const float4*>(W)[
                ((size_t)(og4 * 8 + o_l) * II + i) * 64 + r];
            reinterpret_cast<float4*>(Wl)[o_l * 64 + r] = w4;
        }
        __syncthreads();

        // u[b][i][:] per lane
        float ureg[DD];
        {
            const float4* up = reinterpret_cast<const float4*>(
                u + ((size_t)b * II + i) * DD);
            #pragma unroll
            for (int q = 0; q < 4; ++q) {
                float4 t4 = up[q];
                ureg[4*q+0] = t4.x; ureg[4*q+1] = t4.y;
                ureg[4*q+2] = t4.z; ureg[4*q+3] = t4.w;
            }
        }
        float un2 = 0.f;
        #pragma unroll
        for (int k = 0; k < DD; ++k) un2 += ureg[k] * ureg[k];
        const float unorm = sqrtf(un2);

        #pragma unroll
        for (int ol = 0; ol < 2; ++ol) {
            const int o_l = o2 + ol;
            float uh[DD];
            float n2 = 0.f;
            #pragma unroll
            for (int d2 = 0; d2 < DD; ++d2) {
                float acc = 0.f;
                #pragma unroll
                for (int qq = 0; qq < 4; ++qq) {
                    // wave-uniform address -> broadcast ds_read_b128
                    float4 w4 = reinterpret_cast<const float4*>(Wl)[o_l * 64 + d2 * 4 + qq];
                    acc += w4.x * ureg[4*qq+0] + w4.y * ureg[4*qq+1]
                         + w4.z * ureg[4*qq+2] + w4.w * ureg[4*qq+3];
                }
                uh[d2] = acc;
                n2 += acc * acc;
            }
            const float rawn  = sqrtf(n2);
            const float scale = fminf(rawn, unorm) / (rawn + CAPS_EPS);
            #pragma unroll
            for (int d = 0; d < DD; ++d) {
                uh[d] *= scale;
                s_acc[ol][d] += uh[d];
            }
            // store: [i][o][b][8 pairs] -> lane-contiguous (32 B x 64 lanes = 2 KB)
            unsigned* outp = uhat + (((size_t)i * OO + og4 * 8 + o_l) * BB + b) * 8;
            uint4 p0, p1;
            p0.x = pack_bf16(uh[0],  uh[1]);  p0.y = pack_bf16(uh[2],  uh[3]);
            p0.z = pack_bf16(uh[4],  uh[5]);  p0.w = pack_bf16(uh[6],  uh[7]);
            p1.x = pack_bf16(uh[8],  uh[9]);  p1.y = pack_bf16(uh[10], uh[11]);
            p1.z = pack_bf16(uh[12], uh[13]); p1.w = pack_bf16(uh[14], uh[15]);
            reinterpret_cast<uint4*>(outp)[0] = p0;
            reinterpret_cast<uint4*>(outp)[1] = p1;
        }
    }

    #pragma unroll
    for (int ol = 0; ol < 2; ++ol)
        #pragma unroll
        for (int d = 0; d < DD; ++d)
            part[((size_t)og4 * GXU + blockIdx.x) * 8192 +
                 ((size_t)b * 8 + o2 + ol) * 16 + d] = s_acc[ol][d] * (1.0f / OO);
}

// -------- d-stages: dist = ||v - uhat||, store d, accumulate global sum --------
template<int SLOT>
__global__ __launch_bounds__(256) void dstage_kernel(
    const unsigned* __restrict__ uhat,
    float* __restrict__ ws)
{
    const int og4  = blockIdx.y;
    const int wave = threadIdx.x >> 6;
    const int b    = threadIdx.x & 63;
    const int og   = og4 * 8 + wave * 2;

    float* d_ws       = ws + OFF_D;
    const float* v_ws = ws + OFF_V;

    float vreg[2][DD];
    #pragma unroll
    for (int ol = 0; ol < 2; ++ol) {
        const float4* vp = reinterpret_cast<const float4*>(
            v_ws + ((size_t)b * OO + og + ol) * DD);
        #pragma unroll
        for (int q = 0; q < 4; ++q) {
            float4 t4 = vp[q];
            vreg[ol][4*q+0] = t4.x; vreg[ol][4*q+1] = t4.y;
            vreg[ol][4*q+2] = t4.z; vreg[ol][4*q+3] = t4.w;
        }
    }

    float dsum_local = 0.f;

    #pragma unroll 2
    for (int ii = 0; ii < TID; ++ii) {
        const int i = blockIdx.x * TID + ii;

        float dist[2];
        #pragma unroll
        for (int ol = 0; ol < 2; ++ol) {
            const uint4* up = reinterpret_cast<const uint4*>(
                uhat + (((size_t)i * OO + og + ol) * BB + b) * 8);
            uint4 q0 = up[0], q1 = up[1];
            float dist2 = 0.f;
            #pragma unroll
            for (int j = 0; j < 4; ++j) {
                unsigned w0 = (&q0.x)[j];
                float df0 = vreg[ol][2*j+0] - bf16_lo(w0);
                float df1 = vreg[ol][2*j+1] - bf16_hi(w0);
                dist2 += df0*df0 + df1*df1;
                unsigned w1 = (&q1.x)[j];
                float df2 = vreg[ol][8+2*j+0] - bf16_lo(w1);
                float df3 = vreg[ol][8+2*j+1] - bf16_hi(w1);
                dist2 += df2*df2 + df3*df3;
            }
            dist[ol] = sqrtf(dist2);
        }
        dsum_local += dist[0] + dist[1];
        // d[i][og4][wave][b][2]: lane-contiguous float2 (512 B per wave)
        reinterpret_cast<float2*>(d_ws)[
            (((size_t)i * 4 + og4) * 4 + wave) * BB + b] =
            make_float2(dist[0], dist[1]);
    }

    #pragma unroll
    for (int off = 32; off > 0; off >>= 1)
        dsum_local += __shfl_down(dsum_local, off);
    __shared__ float red[4];
    if (b == 0) red[wave] = dsum_local;
    __syncthreads();
    if (threadIdx.x == 0) {
        float t = red[0] + red[1] + red[2] + red[3];
        atomicAdd(&ws[OFF_DSUM + SLOT], t);
    }
}

// -------- s-stages: softmax(t*d) over o, s partials; STAGE 4 also writes c --------
template<int STAGE>
__global__ __launch_bounds__(256) void sstage_kernel(
    const unsigned* __restrict__ uhat,
    float* __restrict__ ws,
    float* __restrict__ part,
    float* __restrict__ ct)
{
    const int og4  = blockIdx.y;
    const int wave = threadIdx.x >> 6;
    const int b    = threadIdx.x & 63;
    const int o2   = wave * 2;
    const int og   = og4 * 8 + o2;

    const float* d_ws = ws + OFF_D;
    const float tval  = ws[OFF_T + (STAGE == 2 ? 0 : 1)];

    float s_acc[2][DD];
    #pragma unroll
    for (int ol = 0; ol < 2; ++ol)
        #pragma unroll
        for (int d = 0; d < DD; ++d) s_acc[ol][d] = 0.f;

    #pragma unroll 1
    for (int ii = 0; ii < TIS; ++ii) {
        const int i = blockIdx.x * TIS + ii;

        // read all 32 d's for (i,b): 16 coalesced float2 chunks
        float2 dv[16];
        #pragma unroll
        for (int j = 0; j < 16; ++j)
            dv[j] = reinterpret_cast<const float2*>(d_ws)[
                ((size_t)i * 16 + j) * BB + b];

        float m = -1e30f;
        #pragma unroll
        for (int j = 0; j < 16; ++j)
            m = fmaxf(m, fmaxf(tval * dv[j].x, tval * dv[j].y));
        float ssum = 0.f;
        #pragma unroll
        for (int j = 0; j < 16; ++j)
            ssum += __expf(tval * dv[j].x - m) + __expf(tval * dv[j].y - m);
        const float inv = 1.f / ssum;
        const int jown = og4 * 4 + wave;
        const float c0 = __expf(tval * dv[jown].x - m) * inv;
        const float c1 = __expf(tval * dv[jown].y - m) * inv;

        if (STAGE == 4) {
            reinterpret_cast<float2*>(ct)[
                (((size_t)i * 4 + og4) * 4 + wave) * BB + b] = make_float2(c0, c1);
        }

        #pragma unroll
        for (int ol = 0; ol < 2; ++ol) {
            const float cc = ol ? c1 : c0;
            const uint4* up = reinterpret_cast<const uint4*>(
                uhat + (((size_t)i * OO + og + ol) * BB + b) * 8);
            uint4 q0 = up[0], q1 = up[1];
            #pragma unroll
            for (int j = 0; j < 4; ++j) {
                unsigned w0 = (&q0.x)[j];
                s_acc[ol][2*j+0] += cc * bf16_lo(w0);
                s_acc[ol][2*j+1] += cc * bf16_hi(w0);
                unsigned w1 = (&q1.x)[j];
                s_acc[ol][8+2*j+0] += cc * bf16_lo(w1);
                s_acc[ol][8+2*j+1] += cc * bf16_hi(w1);
            }
        }
    }

    #pragma unroll
    for (int ol = 0; ol < 2; ++ol)
        #pragma unroll
        for (int d = 0; d < DD; ++d)
            part[((size_t)og4 * GXS + blockIdx.x) * 8192 +
                 ((size_t)b * 8 + o2 + ol) * 16 + d] = s_acc[ol][d];
}

// -------- reduce partials (+bias) -> squash -> v (or final out) --------
__global__ __launch_bounds__(256) void finv_kernel(
    const float* __restrict__ part, const float* __restrict__ bias,
    float* __restrict__ vout, int GX)
{
    const int tid = blockIdx.x * 256 + threadIdx.x;  // b*512 + o*16 + d
    const int b = tid >> 9, o = (tid >> 4) & 31, d = tid & 15;
    const int og4 = o >> 3, ol = o & 7;
    float s = 0.f;
    for (int ic = 0; ic < GX; ++ic)
        s += part[((size_t)og4 * GX + ic) * 8192 + ((size_t)b * 8 + ol) * 16 + d];
    s += bias[tid & 511];
    float n2 = s * s;
    #pragma unroll
    for (int off = 1; off < 16; off <<= 1) n2 += __shfl_xor(n2, off);
    const float val = s * (n2 / (1.f + n2)) * rsqrtf(n2 + CAPS_EPS);
    vout[tid] = val;
}

__global__ void fint_kernel(float* ws, int slot) {
    if (threadIdx.x == 0 && blockIdx.x == 0) {
        const float d_o = ws[OFF_DSUM + slot] * (1.0f / (float)((size_t)BB * OO * II));
        ws[OFF_T + slot] = T_CONST / (-0.5f * d_o + 1e-12f);
    }
}

// -------- ct [I][og4][w][B][2] -> cout [B][O][I] --------
__global__ __launch_bounds__(256) void transpose_kernel(
    const float* __restrict__ ct, float* __restrict__ dst)
{
    __shared__ float tile[128][33];
    const int t = threadIdx.x;
    const int og4w = blockIdx.y;       // 0..15
    const int i0 = blockIdx.x * 32;    // 64 blocks

    #pragma unroll
    for (int k = 0; k < 16; ++k) {
        const int lin = k * 256 + t;   // 0..4095
        const int r = lin >> 7;        // i_local
        const int c = lin & 127;       // bp = b*2+p
        tile[c][r] = ct[((size_t)(i0 + r) * 16 + og4w) * 128 + c];
    }
    __syncthreads();

    const int col = t & 31;            // i_local
    const int t8 = t >> 5;             // 0..7
    const int og4 = og4w >> 2, w = og4w & 3;
    #pragma unroll
    for (int k = 0; k < 16; ++k) {
        const int row = t8 + k * 8;    // bp
        const int bb = row >> 1, p = row & 1;
        const int o = og4 * 8 + w * 2 + p;
        dst[((size_t)bb * OO + o) * II + i0 + col] = tile[row][col];
    }
}

extern "C" void kernel_launch(void* const* d_in, const int* in_sizes, int n_in,
                              void* d_out, int out_size, void* d_ws, size_t ws_size,
                              hipStream_t stream) {
    const float* u    = (const float*)d_in[0];
    const float* W    = (const float*)d_in[1];
    const float* bias = (const float*)d_in[2];
    float* out = (float*)d_out;
    float* ws  = (float*)d_ws;

    float* part    = ws + OFF_PART;
    float* v_ws    = ws + OFF_V;
    float* ct      = ws + OFF_CT;
    unsigned* uhat = (unsigned*)(ws + OFF_UHAT);
    float* cout    = out + (size_t)BB * OO * DD;

    dim3 blk(256);

    init_kernel<<<1, 64, 0, stream>>>(ws);
    uhat_s0_kernel<<<dim3(GXU, 4), blk, 0, stream>>>(u, W, uhat, part);
    finv_kernel<<<128, 256, 0, stream>>>(part, bias, v_ws, GXU);
    dstage_kernel<0><<<dim3(GXD, 4), blk, 0, stream>>>(uhat, ws);
    fint_kernel<<<1, 64, 0, stream>>>(ws, 0);
    sstage_kernel<2><<<dim3(GXS, 4), blk, 0, stream>>>(uhat, ws, part, ct);
    finv_kernel<<<128, 256, 0, stream>>>(part, bias, v_ws, GXS);
    dstage_kernel<1><<<dim3(GXD, 4), blk, 0, stream>>>(uhat, ws);
    fint_kernel<<<1, 64, 0, stream>>>(ws, 1);
    sstage_kernel<4><<<dim3(GXS, 4), blk, 0, stream>>>(uhat, ws, part, ct);
    finv_kernel<<<128, 256, 0, stream>>>(part, bias, out, GXS);
    transpose_kernel<<<dim3(64, 16), blk, 0, stream>>>(ct, cout);
}

// Round 5
// 376.837 us; speedup vs baseline: 2.9205x; 1.7217x over previous
//
#include <hip/hip_runtime.h>
#include <hip/hip_bf16.h>
#include <math.h>

#define BB 64
#define OO 32
#define II 2048
#define DD 16
#define CAPS_EPS 1e-12f
#define T_CONST 5.6312118f   // ln(0.9*31) - ln(0.1)

#define GXU 256   // uhat: grid (GXU,4), TI=8
#define TIU 8
#define GXD 512   // dstage: grid (GXD,4), TI=4
#define TID 4
#define GXS 256   // sstage: grid (GXS,4), TI=8
#define TIS 8

// workspace float offsets (total 50,364,432 floats = 201,457,728 B <= ws_size)
#define OFF_DSUM 0ULL
#define OFF_V    16ULL                         // 32768: v [B][O][D]
#define OFF_D    (16ULL + 32768ULL)            // 4194304: d [I][j16][B][2]
#define OFF_CT   (OFF_D + 4194304ULL)          // 4194304: c [I][j16][B][2]
#define OFF_UHAT (OFF_CT + 4194304ULL)         // 33554432 slots: uhat bf16 [I][O][B][D]
#define OFF_PART (OFF_UHAT + 33554432ULL)      // 8388608: partials [og4*256+ic][b][8o][16]

__device__ __forceinline__ float bf16_lo(unsigned v) {
    union { unsigned u; float f; } c; c.u = v << 16; return c.f;
}
__device__ __forceinline__ float bf16_hi(unsigned v) {
    union { unsigned u; float f; } c; c.u = v & 0xffff0000u; return c.f;
}
__device__ __forceinline__ unsigned pack_bf16(float a, float b) {
    __hip_bfloat16 ha = __float2bfloat16(a), hb = __float2bfloat16(b);
    unsigned short sa, sb;
    __builtin_memcpy(&sa, &ha, 2); __builtin_memcpy(&sb, &hb, 2);
    return (unsigned)sa | ((unsigned)sb << 16);
}

// -------- pass 1: u_hat (scaled bf16 [i][o][b][d]) + s0 partials (c=1/32) --------
// Wave-private double-buffered LDS W staging: NO __syncthreads, next-i W load
// overlaps current-i compute.
__global__ __launch_bounds__(256) void uhat_s0_kernel(
    const float* __restrict__ u,   // [B][I][16]
    const float* __restrict__ W,   // [O][I][16][16]
    unsigned* __restrict__ uhat,   // [I][O][B][8] packed bf16 pairs
    float* __restrict__ part)
{
    const int og4  = blockIdx.y;
    const int wave = threadIdx.x >> 6;
    const int b    = threadIdx.x & 63;
    const int o0   = og4 * 8 + wave * 2;   // this wave's 2 o's

    __shared__ float4 Wl[4][2][128];       // [wave][buf][o_l*64 + float4_idx]

    const float4* Wv = reinterpret_cast<const float4*>(W);
    const int ibase = blockIdx.x * TIU;

    float s_acc[2][DD];
    #pragma unroll
    for (int ol = 0; ol < 2; ++ol)
        #pragma unroll
        for (int d = 0; d < DD; ++d) s_acc[ol][d] = 0.f;

    // preload W for first i (1 KB per o per wave, lane-coalesced)
    Wl[wave][0][b]      = Wv[((size_t)o0 * II + ibase) * 64 + b];
    Wl[wave][0][64 + b] = Wv[((size_t)(o0 + 1) * II + ibase) * 64 + b];

    for (int ii = 0; ii < TIU; ++ii) {
        const int i = ibase + ii;
        const int cur = ii & 1;
        if (ii + 1 < TIU) {
            const int nxt = cur ^ 1;
            Wl[wave][nxt][b]      = Wv[((size_t)o0 * II + i + 1) * 64 + b];
            Wl[wave][nxt][64 + b] = Wv[((size_t)(o0 + 1) * II + i + 1) * 64 + b];
        }

        float ureg[DD];
        {
            const float4* up = reinterpret_cast<const float4*>(
                u + ((size_t)b * II + i) * DD);
            #pragma unroll
            for (int q = 0; q < 4; ++q) {
                float4 t4 = up[q];
                ureg[4*q+0] = t4.x; ureg[4*q+1] = t4.y;
                ureg[4*q+2] = t4.z; ureg[4*q+3] = t4.w;
            }
        }
        float un2 = 0.f;
        #pragma unroll
        for (int k = 0; k < DD; ++k) un2 += ureg[k] * ureg[k];
        const float unorm = sqrtf(un2);

        #pragma unroll
        for (int ol = 0; ol < 2; ++ol) {
            float uh[DD];
            float n2 = 0.f;
            #pragma unroll
            for (int d2 = 0; d2 < DD; ++d2) {
                float acc = 0.f;
                #pragma unroll
                for (int qq = 0; qq < 4; ++qq) {
                    // wave-uniform LDS address -> broadcast ds_read_b128
                    float4 w4 = Wl[wave][cur][ol * 64 + d2 * 4 + qq];
                    acc += w4.x * ureg[4*qq+0] + w4.y * ureg[4*qq+1]
                         + w4.z * ureg[4*qq+2] + w4.w * ureg[4*qq+3];
                }
                uh[d2] = acc;
                n2 += acc * acc;
            }
            const float rawn  = sqrtf(n2);
            const float scale = fminf(rawn, unorm) / (rawn + CAPS_EPS);
            #pragma unroll
            for (int d = 0; d < DD; ++d) {
                uh[d] *= scale;
                s_acc[ol][d] += uh[d];
            }
            unsigned* outp = uhat + (((size_t)i * OO + o0 + ol) * BB + b) * 8;
            uint4 p0, p1;
            p0.x = pack_bf16(uh[0],  uh[1]);  p0.y = pack_bf16(uh[2],  uh[3]);
            p0.z = pack_bf16(uh[4],  uh[5]);  p0.w = pack_bf16(uh[6],  uh[7]);
            p1.x = pack_bf16(uh[8],  uh[9]);  p1.y = pack_bf16(uh[10], uh[11]);
            p1.z = pack_bf16(uh[12], uh[13]); p1.w = pack_bf16(uh[14], uh[15]);
            reinterpret_cast<uint4*>(outp)[0] = p0;
            reinterpret_cast<uint4*>(outp)[1] = p1;
        }
    }

    #pragma unroll
    for (int ol = 0; ol < 2; ++ol)
        #pragma unroll
        for (int d = 0; d < DD; ++d)
            part[((size_t)og4 * GXU + blockIdx.x) * 8192 +
                 ((size_t)b * 8 + wave * 2 + ol) * 16 + d] = s_acc[ol][d] * (1.0f / OO);
}

// -------- d-stages: dist = ||v - uhat||, store d [i][j16][b][2], global dsum --------
template<int SLOT>
__global__ __launch_bounds__(256) void dstage_kernel(
    const unsigned* __restrict__ uhat,
    float* __restrict__ ws)
{
    const int og4  = blockIdx.y;
    const int wave = threadIdx.x >> 6;
    const int b    = threadIdx.x & 63;
    const int og   = og4 * 8 + wave * 2;

    float* d_ws       = ws + OFF_D;
    const float* v_ws = ws + OFF_V;

    float vreg[2][DD];
    #pragma unroll
    for (int ol = 0; ol < 2; ++ol) {
        const float4* vp = reinterpret_cast<const float4*>(
            v_ws + ((size_t)b * OO + og + ol) * DD);
        #pragma unroll
        for (int q = 0; q < 4; ++q) {
            float4 t4 = vp[q];
            vreg[ol][4*q+0] = t4.x; vreg[ol][4*q+1] = t4.y;
            vreg[ol][4*q+2] = t4.z; vreg[ol][4*q+3] = t4.w;
        }
    }

    float dsum_local = 0.f;

    #pragma unroll
    for (int ii = 0; ii < TID; ++ii) {
        const int i = blockIdx.x * TID + ii;

        float dist[2];
        #pragma unroll
        for (int ol = 0; ol < 2; ++ol) {
            const uint4* up = reinterpret_cast<const uint4*>(
                uhat + (((size_t)i * OO + og + ol) * BB + b) * 8);
            uint4 q0 = up[0], q1 = up[1];
            float dist2 = 0.f;
            #pragma unroll
            for (int j = 0; j < 4; ++j) {
                unsigned w0 = (&q0.x)[j];
                float df0 = vreg[ol][2*j+0] - bf16_lo(w0);
                float df1 = vreg[ol][2*j+1] - bf16_hi(w0);
                dist2 += df0*df0 + df1*df1;
                unsigned w1 = (&q1.x)[j];
                float df2 = vreg[ol][8+2*j+0] - bf16_lo(w1);
                float df3 = vreg[ol][8+2*j+1] - bf16_hi(w1);
                dist2 += df2*df2 + df3*df3;
            }
            dist[ol] = sqrtf(dist2);
        }
        dsum_local += dist[0] + dist[1];
        reinterpret_cast<float2*>(d_ws)[
            ((size_t)i * 16 + og4 * 4 + wave) * BB + b] =
            make_float2(dist[0], dist[1]);
    }

    #pragma unroll
    for (int off = 32; off > 0; off >>= 1)
        dsum_local += __shfl_down(dsum_local, off);
    __shared__ float red[4];
    if (b == 0) red[wave] = dsum_local;
    __syncthreads();
    if (threadIdx.x == 0) {
        float t = red[0] + red[1] + red[2] + red[3];
        atomicAdd(&ws[OFF_DSUM + SLOT], t);
    }
}

// -------- csoft: c[i][j16][b][2] = softmax(t*d) over o, t computed inline --------
template<int SLOT>
__global__ __launch_bounds__(256) void csoft_kernel(
    const float* __restrict__ ws_c, float* __restrict__ cbuf)
{
    const int wave = threadIdx.x >> 6;
    const int b    = threadIdx.x & 63;
    const int i    = blockIdx.x * 4 + wave;

    const float* d_ws = ws_c + OFF_D;
    const float dsum  = ws_c[OFF_DSUM + SLOT];
    const float tval  = T_CONST / (-0.5f * dsum * (1.0f / 4194304.0f) + 1e-12f);

    float dv[OO];
    #pragma unroll
    for (int j = 0; j < 16; ++j) {
        float2 x = reinterpret_cast<const float2*>(d_ws)[((size_t)i * 16 + j) * BB + b];
        dv[2*j]   = tval * x.x;
        dv[2*j+1] = tval * x.y;
    }
    float m = -1e30f;
    #pragma unroll
    for (int o = 0; o < OO; ++o) m = fmaxf(m, dv[o]);
    float ssum = 0.f;
    #pragma unroll
    for (int o = 0; o < OO; ++o) { dv[o] = __expf(dv[o] - m); ssum += dv[o]; }
    const float inv = 1.f / ssum;
    #pragma unroll
    for (int j = 0; j < 16; ++j)
        reinterpret_cast<float2*>(cbuf)[((size_t)i * 16 + j) * BB + b] =
            make_float2(dv[2*j] * inv, dv[2*j+1] * inv);
}

// -------- s-stages: s partials = sum_i c * uhat (no softmax, no spill) --------
__global__ __launch_bounds__(256) void sstage_kernel(
    const unsigned* __restrict__ uhat,
    const float* __restrict__ cbuf,
    float* __restrict__ part)
{
    const int og4  = blockIdx.y;
    const int wave = threadIdx.x >> 6;
    const int b    = threadIdx.x & 63;
    const int og   = og4 * 8 + wave * 2;
    const int jown = og4 * 4 + wave;

    float s_acc[2][DD];
    #pragma unroll
    for (int ol = 0; ol < 2; ++ol)
        #pragma unroll
        for (int d = 0; d < DD; ++d) s_acc[ol][d] = 0.f;

    #pragma unroll 2
    for (int ii = 0; ii < TIS; ++ii) {
        const int i = blockIdx.x * TIS + ii;

        const float2 c2 = reinterpret_cast<const float2*>(cbuf)[
            ((size_t)i * 16 + jown) * BB + b];

        #pragma unroll
        for (int ol = 0; ol < 2; ++ol) {
            const float cc = ol ? c2.y : c2.x;
            const uint4* up = reinterpret_cast<const uint4*>(
                uhat + (((size_t)i * OO + og + ol) * BB + b) * 8);
            uint4 q0 = up[0], q1 = up[1];
            #pragma unroll
            for (int j = 0; j < 4; ++j) {
                unsigned w0 = (&q0.x)[j];
                s_acc[ol][2*j+0] += cc * bf16_lo(w0);
                s_acc[ol][2*j+1] += cc * bf16_hi(w0);
                unsigned w1 = (&q1.x)[j];
                s_acc[ol][8+2*j+0] += cc * bf16_lo(w1);
                s_acc[ol][8+2*j+1] += cc * bf16_hi(w1);
            }
        }
    }

    #pragma unroll
    for (int ol = 0; ol < 2; ++ol)
        #pragma unroll
        for (int d = 0; d < DD; ++d)
            part[((size_t)og4 * GXS + blockIdx.x) * 8192 +
                 ((size_t)b * 8 + wave * 2 + ol) * 16 + d] = s_acc[ol][d];
}

// -------- reduce partials (+bias) -> squash -> v/out; also zero next dsum slot --------
template<int ZSLOT>
__global__ __launch_bounds__(256) void finv_kernel(
    const float* __restrict__ part, const float* __restrict__ bias,
    float* __restrict__ vout, float* __restrict__ ws)
{
    if (ZSLOT >= 0 && blockIdx.x == 0 && threadIdx.x == 0)
        ws[OFF_DSUM + ZSLOT] = 0.f;
    const int tid = blockIdx.x * 256 + threadIdx.x;  // b*512 + o*16 + d
    const int b = tid >> 9, o = (tid >> 4) & 31, d = tid & 15;
    const int og4 = o >> 3, ol = o & 7;
    float s = 0.f;
    for (int ic = 0; ic < 256; ++ic)
        s += part[((size_t)og4 * 256 + ic) * 8192 + ((size_t)b * 8 + ol) * 16 + d];
    s += bias[tid & 511];
    float n2 = s * s;
    #pragma unroll
    for (int off = 1; off < 16; off <<= 1) n2 += __shfl_xor(n2, off);
    const float val = s * (n2 / (1.f + n2)) * rsqrtf(n2 + CAPS_EPS);
    vout[tid] = val;
}

// -------- c [I][j16][B][2] -> cout [B][O][I] --------
__global__ __launch_bounds__(256) void transpose_kernel(
    const float* __restrict__ ct, float* __restrict__ dst)
{
    __shared__ float tile[128][33];
    const int t = threadIdx.x;
    const int og4w = blockIdx.y;       // j index 0..15
    const int i0 = blockIdx.x * 32;

    #pragma unroll
    for (int k = 0; k < 16; ++k) {
        const int lin = k * 256 + t;
        const int r = lin >> 7;        // i_local
        const int c = lin & 127;       // bp = b*2+p
        tile[c][r] = ct[((size_t)(i0 + r) * 16 + og4w) * 128 + c];
    }
    __syncthreads();

    const int col = t & 31;            // i_local
    const int t8 = t >> 5;             // 0..7
    const int og4 = og4w >> 2, w = og4w & 3;
    #pragma unroll
    for (int k = 0; k < 16; ++k) {
        const int row = t8 + k * 8;    // bp
        const int bb = row >> 1, p = row & 1;
        const int o = og4 * 8 + w * 2 + p;
        dst[((size_t)bb * OO + o) * II + i0 + col] = tile[row][col];
    }
}

extern "C" void kernel_launch(void* const* d_in, const int* in_sizes, int n_in,
                              void* d_out, int out_size, void* d_ws, size_t ws_size,
                              hipStream_t stream) {
    const float* u    = (const float*)d_in[0];
    const float* W    = (const float*)d_in[1];
    const float* bias = (const float*)d_in[2];
    float* out = (float*)d_out;
    float* ws  = (float*)d_ws;

    float* part    = ws + OFF_PART;
    float* v_ws    = ws + OFF_V;
    float* cbuf    = ws + OFF_CT;
    unsigned* uhat = (unsigned*)(ws + OFF_UHAT);
    float* cout    = out + (size_t)BB * OO * DD;

    dim3 blk(256);

    uhat_s0_kernel<<<dim3(GXU, 4), blk, 0, stream>>>(u, W, uhat, part);
    finv_kernel<0><<<128, blk, 0, stream>>>(part, bias, v_ws, ws);
    dstage_kernel<0><<<dim3(GXD, 4), blk, 0, stream>>>(uhat, ws);
    csoft_kernel<0><<<512, blk, 0, stream>>>(ws, cbuf);
    sstage_kernel<<<dim3(GXS, 4), blk, 0, stream>>>(uhat, cbuf, part);
    finv_kernel<1><<<128, blk, 0, stream>>>(part, bias, v_ws, ws);
    dstage_kernel<1><<<dim3(GXD, 4), blk, 0, stream>>>(uhat, ws);
    csoft_kernel<1><<<512, blk, 0, stream>>>(ws, cbuf);
    sstage_kernel<<<dim3(GXS, 4), blk, 0, stream>>>(uhat, cbuf, part);
    finv_kernel<-1><<<128, blk, 0, stream>>>(part, bias, out, ws);
    transpose_kernel<<<dim3(64, 16), blk, 0, stream>>>(cbuf, cout);
}

// Round 6
// 332.063 us; speedup vs baseline: 3.3143x; 1.1348x over previous
//
#include <hip/hip_runtime.h>
#include <hip/hip_bf16.h>
#include <math.h>

#define BB 64
#define OO 32
#define II 2048
#define DD 16
#define CAPS_EPS 1e-12f
#define T_CONST 5.6312118f   // ln(0.9*31) - ln(0.1)

#define GX 128               // i-chunks for s/d passes
#define TI 16                // II/GX

// workspace float offsets (total ~22.2M floats = 89 MB; ws >= 201 MB proven R2+)
#define OFF_DSUM 0ULL
#define OFF_V     16ULL                        // 32768: v [B][O][D]
#define OFF_UNORM 32784ULL                     // 131072: unorm [I][B]
#define OFF_UBF   163856ULL                    // 1048576 slots: u bf16 [I][B][16k]
#define OFF_WB    1212432ULL                   // 8388608 slots: W bf16 A-frag [O][I][2q][16m][8j]
#define OFF_DD    9601040ULL                   // 4194304: d [I][O][B]
#define OFF_CB    13795344ULL                  // 4194304: c [I][O][B]
#define OFF_PART  17989648ULL                  // 4194304: part [GX][O][B][D]

typedef __attribute__((ext_vector_type(8))) short bf16x8;
typedef __attribute__((ext_vector_type(4))) float f32x4;

union AU { bf16x8 v; unsigned short h[8]; uint4 u4; };

__device__ __forceinline__ unsigned short f2bf(float x) {
    __hip_bfloat16 h = __float2bfloat16(x);
    unsigned short s; __builtin_memcpy(&s, &h, 2); return s;
}

// -------- uprep: u -> bf16 [i][b][16], unorm[i][b], zero dsums --------
__global__ __launch_bounds__(256) void uprep_kernel(
    const float* __restrict__ u, float* __restrict__ ws)
{
    const int gid = blockIdx.x * 256 + threadIdx.x;   // 131072
    if (gid < 2) ws[OFF_DSUM + gid] = 0.f;
    const int i = gid >> 6, b = gid & 63;

    const float4* up = reinterpret_cast<const float4*>(u + ((size_t)b * II + i) * DD);
    float4 t0 = up[0], t1 = up[1], t2 = up[2], t3 = up[3];
    float un2 = t0.x*t0.x + t0.y*t0.y + t0.z*t0.z + t0.w*t0.w
              + t1.x*t1.x + t1.y*t1.y + t1.z*t1.z + t1.w*t1.w
              + t2.x*t2.x + t2.y*t2.y + t2.z*t2.z + t2.w*t2.w
              + t3.x*t3.x + t3.y*t3.y + t3.z*t3.z + t3.w*t3.w;
    ws[OFF_UNORM + (size_t)i * 64 + b] = sqrtf(un2);

    AU a0, a1;
    a0.h[0]=f2bf(t0.x); a0.h[1]=f2bf(t0.y); a0.h[2]=f2bf(t0.z); a0.h[3]=f2bf(t0.w);
    a0.h[4]=f2bf(t1.x); a0.h[5]=f2bf(t1.y); a0.h[6]=f2bf(t1.z); a0.h[7]=f2bf(t1.w);
    a1.h[0]=f2bf(t2.x); a1.h[1]=f2bf(t2.y); a1.h[2]=f2bf(t2.z); a1.h[3]=f2bf(t2.w);
    a1.h[4]=f2bf(t3.x); a1.h[5]=f2bf(t3.y); a1.h[6]=f2bf(t3.z); a1.h[7]=f2bf(t3.w);
    unsigned short* ubf = (unsigned short*)(ws + OFF_UBF);
    uint4* dst = reinterpret_cast<uint4*>(ubf + ((size_t)i * 64 + b) * 16);
    dst[0] = a0.u4; dst[1] = a1.u4;
}

// -------- s0w: W fp32 -> Wb bf16 (A-layout) + MFMA uhat + s0 partials --------
__global__ __launch_bounds__(256) void s0w_kernel(
    const float* __restrict__ W, float* __restrict__ ws)
{
    const int og   = blockIdx.y;
    const int wave = threadIdx.x >> 6;
    const int lane = threadIdx.x & 63;
    const int o    = og * 4 + wave;
    const int q    = lane >> 4;
    const int n    = lane & 15;

    unsigned short* Wb = (unsigned short*)(ws + OFF_WB);
    const unsigned short* ubf = (const unsigned short*)(ws + OFF_UBF);
    const float* unorm = ws + OFF_UNORM;
    float* part = ws + OFF_PART;

    f32x4 s_acc[4];
    #pragma unroll
    for (int g = 0; g < 4; ++g) s_acc[g] = (f32x4){0.f, 0.f, 0.f, 0.f};

    for (int ii = 0; ii < TI; ++ii) {
        const int i = blockIdx.x * TI + ii;

        AU au; au.u4 = make_uint4(0, 0, 0, 0);
        if (q < 2) {
            const float* wp = W + (((size_t)o * II + i) * 16 + n) * 16 + q * 8;
            float4 w0 = *(const float4*)(wp);
            float4 w1 = *(const float4*)(wp + 4);
            au.h[0]=f2bf(w0.x); au.h[1]=f2bf(w0.y); au.h[2]=f2bf(w0.z); au.h[3]=f2bf(w0.w);
            au.h[4]=f2bf(w1.x); au.h[5]=f2bf(w1.y); au.h[6]=f2bf(w1.z); au.h[7]=f2bf(w1.w);
            *reinterpret_cast<uint4*>(Wb + (((size_t)o * II + i) * 2 + q) * 128 + n * 8) = au.u4;
        }

        f32x4 d4[4];
        #pragma unroll
        for (int g = 0; g < 4; ++g) {
            AU bu;
            bu.u4 = *reinterpret_cast<const uint4*>(
                ubf + ((size_t)i * 64 + g * 16 + n) * 16 + (q & 1) * 8);
            d4[g] = __builtin_amdgcn_mfma_f32_16x16x32_bf16(
                au.v, bu.v, (f32x4){0.f, 0.f, 0.f, 0.f}, 0, 0, 0);
        }

        #pragma unroll
        for (int g = 0; g < 4; ++g) {
            float n2 = d4[g][0]*d4[g][0] + d4[g][1]*d4[g][1]
                     + d4[g][2]*d4[g][2] + d4[g][3]*d4[g][3];
            n2 += __shfl_xor(n2, 16);
            n2 += __shfl_xor(n2, 32);
            const float rawn = sqrtf(n2);
            const float un = unorm[(size_t)i * 64 + g * 16 + n];
            const float cs = (1.0f / 32.0f) * fminf(rawn, un) / (rawn + CAPS_EPS);
            s_acc[g][0] += cs * d4[g][0];
            s_acc[g][1] += cs * d4[g][1];
            s_acc[g][2] += cs * d4[g][2];
            s_acc[g][3] += cs * d4[g][3];
        }
    }

    #pragma unroll
    for (int g = 0; g < 4; ++g) {
        float4 v = make_float4(s_acc[g][0], s_acc[g][1], s_acc[g][2], s_acc[g][3]);
        *reinterpret_cast<float4*>(
            part + (((size_t)blockIdx.x * OO + o) * 64 + g * 16 + n) * 16 + q * 4) = v;
    }
}

// -------- dpass: dist[i][o][b] = ||v - uhat||, atomic dsum --------
template<int SLOT>
__global__ __launch_bounds__(256) void dpass_kernel(float* __restrict__ ws)
{
    const int og   = blockIdx.y;
    const int wave = threadIdx.x >> 6;
    const int lane = threadIdx.x & 63;
    const int o    = og * 4 + wave;
    const int q    = lane >> 4;
    const int n    = lane & 15;

    const unsigned short* Wb  = (const unsigned short*)(ws + OFF_WB);
    const unsigned short* ubf = (const unsigned short*)(ws + OFF_UBF);
    const float* unorm = ws + OFF_UNORM;
    const float* v_ws  = ws + OFF_V;
    float* dws = ws + OFF_DD;

    f32x4 vreg[4];
    #pragma unroll
    for (int g = 0; g < 4; ++g)
        vreg[g] = *reinterpret_cast<const f32x4*>(
            v_ws + ((size_t)(g * 16 + n) * OO + o) * 16 + q * 4);

    float dsum_local = 0.f;

    for (int ii = 0; ii < TI; ++ii) {
        const int i = blockIdx.x * TI + ii;

        AU au; au.u4 = make_uint4(0, 0, 0, 0);
        if (q < 2)
            au.u4 = *reinterpret_cast<const uint4*>(
                Wb + (((size_t)o * II + i) * 2 + q) * 128 + n * 8);

        f32x4 d4[4];
        #pragma unroll
        for (int g = 0; g < 4; ++g) {
            AU bu;
            bu.u4 = *reinterpret_cast<const uint4*>(
                ubf + ((size_t)i * 64 + g * 16 + n) * 16 + (q & 1) * 8);
            d4[g] = __builtin_amdgcn_mfma_f32_16x16x32_bf16(
                au.v, bu.v, (f32x4){0.f, 0.f, 0.f, 0.f}, 0, 0, 0);
        }

        #pragma unroll
        for (int g = 0; g < 4; ++g) {
            float n2 = d4[g][0]*d4[g][0] + d4[g][1]*d4[g][1]
                     + d4[g][2]*d4[g][2] + d4[g][3]*d4[g][3];
            n2 += __shfl_xor(n2, 16);
            n2 += __shfl_xor(n2, 32);
            const float rawn = sqrtf(n2);
            const float un = unorm[(size_t)i * 64 + g * 16 + n];
            const float scale = fminf(rawn, un) / (rawn + CAPS_EPS);
            float dd2 = 0.f;
            #pragma unroll
            for (int r = 0; r < 4; ++r) {
                float df = vreg[g][r] - scale * d4[g][r];
                dd2 += df * df;
            }
            dd2 += __shfl_xor(dd2, 16);
            dd2 += __shfl_xor(dd2, 32);
            const float dist = sqrtf(dd2);
            if (q == 0)
                dws[((size_t)i * OO + o) * 64 + g * 16 + n] = dist;
            dsum_local += (q == 0) ? dist : 0.f;
        }
    }

    #pragma unroll
    for (int off = 32; off > 0; off >>= 1)
        dsum_local += __shfl_down(dsum_local, off);
    __shared__ float red[4];
    if (lane == 0) red[wave] = dsum_local;
    __syncthreads();
    if (threadIdx.x == 0)
        atomicAdd(&ws[OFF_DSUM + SLOT], red[0] + red[1] + red[2] + red[3]);
}

// -------- csoft: c[i][o][b] = softmax_o(t * d), t from global dsum --------
template<int SLOT>
__global__ __launch_bounds__(256) void csoft_kernel(float* __restrict__ ws)
{
    const int wave = threadIdx.x >> 6;
    const int b    = threadIdx.x & 63;
    const int i    = blockIdx.x * 4 + wave;

    const float* dws = ws + OFF_DD;
    float* cb = ws + OFF_CB;
    const float dsum = ws[OFF_DSUM + SLOT];
    const float tval = T_CONST / (-0.5f * dsum * (1.0f / 4194304.0f) + 1e-12f);

    float dv[OO];
    #pragma unroll
    for (int o = 0; o < OO; ++o)
        dv[o] = tval * dws[((size_t)i * OO + o) * 64 + b];
    float m = -1e30f;
    #pragma unroll
    for (int o = 0; o < OO; ++o) m = fmaxf(m, dv[o]);
    float ssum = 0.f;
    #pragma unroll
    for (int o = 0; o < OO; ++o) { dv[o] = __expf(dv[o] - m); ssum += dv[o]; }
    const float inv = 1.f / ssum;
    #pragma unroll
    for (int o = 0; o < OO; ++o)
        cb[((size_t)i * OO + o) * 64 + b] = dv[o] * inv;
}

// -------- spass: s partials = sum_i c * uhat (MFMA recompute) --------
__global__ __launch_bounds__(256) void spass_kernel(float* __restrict__ ws)
{
    const int og   = blockIdx.y;
    const int wave = threadIdx.x >> 6;
    const int lane = threadIdx.x & 63;
    const int o    = og * 4 + wave;
    const int q    = lane >> 4;
    const int n    = lane & 15;

    const unsigned short* Wb  = (const unsigned short*)(ws + OFF_WB);
    const unsigned short* ubf = (const unsigned short*)(ws + OFF_UBF);
    const float* unorm = ws + OFF_UNORM;
    const float* cb = ws + OFF_CB;
    float* part = ws + OFF_PART;

    f32x4 s_acc[4];
    #pragma unroll
    for (int g = 0; g < 4; ++g) s_acc[g] = (f32x4){0.f, 0.f, 0.f, 0.f};

    for (int ii = 0; ii < TI; ++ii) {
        const int i = blockIdx.x * TI + ii;

        AU au; au.u4 = make_uint4(0, 0, 0, 0);
        if (q < 2)
            au.u4 = *reinterpret_cast<const uint4*>(
                Wb + (((size_t)o * II + i) * 2 + q) * 128 + n * 8);

        f32x4 d4[4];
        #pragma unroll
        for (int g = 0; g < 4; ++g) {
            AU bu;
            bu.u4 = *reinterpret_cast<const uint4*>(
                ubf + ((size_t)i * 64 + g * 16 + n) * 16 + (q & 1) * 8);
            d4[g] = __builtin_amdgcn_mfma_f32_16x16x32_bf16(
                au.v, bu.v, (f32x4){0.f, 0.f, 0.f, 0.f}, 0, 0, 0);
        }

        #pragma unroll
        for (int g = 0; g < 4; ++g) {
            float n2 = d4[g][0]*d4[g][0] + d4[g][1]*d4[g][1]
                     + d4[g][2]*d4[g][2] + d4[g][3]*d4[g][3];
            n2 += __shfl_xor(n2, 16);
            n2 += __shfl_xor(n2, 32);
            const float rawn = sqrtf(n2);
            const float un = unorm[(size_t)i * 64 + g * 16 + n];
            const float cc = cb[((size_t)i * OO + o) * 64 + g * 16 + n];
            const float cs = cc * fminf(rawn, un) / (rawn + CAPS_EPS);
            s_acc[g][0] += cs * d4[g][0];
            s_acc[g][1] += cs * d4[g][1];
            s_acc[g][2] += cs * d4[g][2];
            s_acc[g][3] += cs * d4[g][3];
        }
    }

    #pragma unroll
    for (int g = 0; g < 4; ++g) {
        float4 v = make_float4(s_acc[g][0], s_acc[g][1], s_acc[g][2], s_acc[g][3]);
        *reinterpret_cast<float4*>(
            part + (((size_t)blockIdx.x * OO + o) * 64 + g * 16 + n) * 16 + q * 4) = v;
    }
}

// -------- finv: reduce part (+bias) -> squash -> vout --------
__global__ __launch_bounds__(256) void finv_kernel(
    const float* __restrict__ part, const float* __restrict__ bias,
    float* __restrict__ vout)
{
    const int tid = blockIdx.x * 256 + threadIdx.x;  // b*512 + o*16 + d
    const int b = tid >> 9, o = (tid >> 4) & 31, d = tid & 15;
    float s = 0.f;
    for (int ic = 0; ic < GX; ++ic)
        s += part[(((size_t)ic * OO + o) * 64 + b) * 16 + d];
    s += bias[tid & 511];
    float n2 = s * s;
    #pragma unroll
    for (int off = 1; off < 16; off <<= 1) n2 += __shfl_xor(n2, off);
    vout[tid] = s * (n2 / (1.f + n2)) * rsqrtf(n2 + CAPS_EPS);
}

// -------- transpose: c [I][O][B] -> out [B][O][I] --------
__global__ __launch_bounds__(256) void transpose_kernel(
    const float* __restrict__ cb, float* __restrict__ dst)
{
    __shared__ float tile[32][65];
    const int o  = blockIdx.y;
    const int i0 = blockIdx.x * 32;
    #pragma unroll
    for (int k = 0; k < 8; ++k) {
        const int lin = k * 256 + threadIdx.x;
        const int r = lin >> 6, b = lin & 63;
        tile[r][b] = cb[((size_t)(i0 + r) * OO + o) * 64 + b];
    }
    __syncthreads();
    #pragma unroll
    for (int k = 0; k < 8; ++k) {
        const int lin = k * 256 + threadIdx.x;
        const int b = lin >> 5, r = lin & 31;
        dst[((size_t)b * OO + o) * II + i0 + r] = tile[r][b];
    }
}

extern "C" void kernel_launch(void* const* d_in, const int* in_sizes, int n_in,
                              void* d_out, int out_size, void* d_ws, size_t ws_size,
                              hipStream_t stream) {
    const float* u    = (const float*)d_in[0];
    const float* W    = (const float*)d_in[1];
    const float* bias = (const float*)d_in[2];
    float* out = (float*)d_out;
    float* ws  = (float*)d_ws;

    float* part = ws + OFF_PART;
    float* v_ws = ws + OFF_V;
    float* cb   = ws + OFF_CB;
    float* cout = out + (size_t)BB * OO * DD;

    dim3 blk(256);
    dim3 grid_m(GX, 8);

    uprep_kernel<<<512, blk, 0, stream>>>(u, ws);
    s0w_kernel<<<grid_m, blk, 0, stream>>>(W, ws);
    finv_kernel<<<128, blk, 0, stream>>>(part, bias, v_ws);
    dpass_kernel<0><<<grid_m, blk, 0, stream>>>(ws);
    csoft_kernel<0><<<512, blk, 0, stream>>>(ws);
    spass_kernel<<<grid_m, blk, 0, stream>>>(ws);
    finv_kernel<<<128, blk, 0, stream>>>(part, bias, v_ws);
    dpass_kernel<1><<<grid_m, blk, 0, stream>>>(ws);
    csoft_kernel<1><<<512, blk, 0, stream>>>(ws);
    spass_kernel<<<grid_m, blk, 0, stream>>>(ws);
    finv_kernel<<<128, blk, 0, stream>>>(part, bias, out);
    transpose_kernel<<<dim3(64, 32), blk, 0, stream>>>(cb, cout);
}